// Round 7
// baseline (140.110 us; speedup 1.0000x reference)
//
#include <hip/hip_runtime.h>
#include <hip/hip_bf16.h>

#define NS_TOT 2000
#define NA 1000
#define NI 5
#define NH 32
#define SHALF 1000                 // structs per block (two blocks per atom)

typedef __attribute__((ext_vector_type(8)))  short short8;   // 8 bf16 = 4 VGPR
typedef __attribute__((ext_vector_type(16))) float f32x16;   // MFMA 32x32 acc

// tanh(x) = 1 - 2/(exp(2x)+1). Saturates correctly; ~1e-6 abs err.
__device__ __forceinline__ float fast_tanh(float x) {
    float E = __expf(2.0f * x);
    float r = __builtin_amdgcn_rcpf(E + 1.0f);
    return fmaf(-2.0f, r, 1.0f);
}

__device__ __forceinline__ float4 ffma4(float s, float4 w, float4 acc) {
    acc.x = fmaf(s, w.x, acc.x);
    acc.y = fmaf(s, w.y, acc.y);
    acc.z = fmaf(s, w.z, acc.z);
    acc.w = fmaf(s, w.w, acc.w);
    return acc;
}

#define TANH4(v) { (v).x = fast_tanh((v).x); (v).y = fast_tanh((v).y); \
                   (v).z = fast_tanh((v).z); (v).w = fast_tanh((v).w); }

__device__ __forceinline__ unsigned short f2bf_rne(float x) {
    unsigned u = __float_as_uint(x);
    unsigned r = u + 0x7FFFu + ((u >> 16) & 1u);
    return (unsigned short)(r >> 16);
}

__device__ __forceinline__ unsigned pack2(float a, float b) {
    __hip_bfloat162 p = __float22bfloat162_rn(make_float2(a, b));
    unsigned u; __builtin_memcpy(&u, &p, 4); return u;
}

// R6 -> R7: same compute structure (layer1 VALU w/ scalar weights, bf16 pack,
// wave-private LDS stage, 2x mfma_32x32x16_bf16, tanh+dot epilogue). Change is
// RESIDENCY: R6 had 1000 blocks @ waves_per_eu(4,4) = whole grid co-resident
// in one round, Occupancy 28% (drain-dominated), VALUBusy 70%. Now: 2000
// blocks (atom x s-half, 4 iters each) and waves_per_eu(4,8): min=4 keeps the
// 128-VGPR allocator budget (kernel uses 52 -> no spill regression), max=8
// lets 7 blocks/CU be resident (LDS 23040*7 = 161KB <= 163840B).
__global__ __attribute__((amdgpu_flat_work_group_size(256, 256),
                          amdgpu_waves_per_eu(4, 8)))
void mlp_mfma(
    const float* __restrict__ g,
    const float* __restrict__ W1, const float* __restrict__ b1,
    const float* __restrict__ W2, const float* __restrict__ b2,
    const float* __restrict__ W3, const float* __restrict__ b3,
    float* __restrict__ out)
{
    const int bid   = blockIdx.x;
    const int araw  = bid % NA;
    const int chunk = bid / NA;              // 0 or 1: which s-half
    // XCD swizzle: consecutive atoms (sharing 64B lines of g/out) -> same XCD.
    const int a = (araw >> 3) + 125 * (araw & 7);   // NA = 8*125
    const int t = threadIdx.x;
    const int lane = t & 63, wid = t >> 6;
    const int l31 = lane & 31, half = lane >> 5;

    const int sbase_blk = chunk * SHALF;
    const int send      = sbase_blk + SHALF;        // <= NS_TOT

    __shared__ __align__(16) unsigned short sW2T[NH * NH];   // W2^T bf16 [m][k]
    __shared__ __align__(16) float sB2[NH];
    __shared__ __align__(16) float sW3[NH];
    // per-wave h1 stage: 64 structs x 32 bf16, row stride 40 ushort (80B):
    // start banks 20*l % 32 tile all 32 banks evenly -> b128 ops conflict-free.
    __shared__ __align__(16) unsigned short sH[4][64 * 40];

    // ---- stage W2^T (bf16), b2, W3 ----
    for (int idx = t; idx < NH * NH; idx += 256) {
        const int i = idx >> 5, j = idx & 31;            // W2[i][j]
        sW2T[j * NH + i] = f2bf_rne(W2[(size_t)a * NH * NH + idx]);
    }
    if (t < NH) { sB2[t] = b2[a * NH + t]; sW3[t] = W3[a * NH + t]; }
    __syncthreads();

    // ---- persistent per-lane fragments ----
    // A[m=l31][k=half*8+j] = W2[k][m]; second k-step at k+16.
    const short8 af0 = __builtin_bit_cast(short8, *(const uint4*)(sW2T + l31 * NH + half * 8));
    const short8 af1 = __builtin_bit_cast(short8, *(const uint4*)(sW2T + l31 * NH + 16 + half * 8));
    // C-layout: col=lane&31, row=(r&3)+8*(r>>2)+4*half (m74/m101-verified)
    const float4 b2q0 = ((const float4*)sB2)[0 + half];
    const float4 b2q1 = ((const float4*)sB2)[2 + half];
    const float4 b2q2 = ((const float4*)sB2)[4 + half];
    const float4 b2q3 = ((const float4*)sB2)[6 + half];
    const float4 w3q0 = ((const float4*)sW3)[0 + half];
    const float4 w3q1 = ((const float4*)sW3)[2 + half];
    const float4 w3q2 = ((const float4*)sW3)[4 + half];
    const float4 w3q3 = ((const float4*)sW3)[6 + half];
    const float bias3 = b3[a];

    // wave-uniform layer1 weight bases -> scalar loads (R5-proven path)
    const float4* w1v = (const float4*)(W1 + (size_t)a * NI * NH);
    const float4* b1v = (const float4*)(b1 + (size_t)a * NH);

    unsigned short* hrow = sH[wid];

    for (int it = 0; it < 4; ++it) {
        const int base = sbase_blk + it * 256 + wid * 64;
        const int s = base + lane;
        const int sl = (s < send) ? s : (send - 1);  // tail: duplicate work

        const float* gp = g + ((size_t)sl * NA + a) * NI;
        const float x0g = gp[0], x1g = gp[1], x2g = gp[2], x3g = gp[3], x4g = gp[4];

        // ---- layer 1: 5 -> 32 (VALU, scalar weights) ----
        float4 h[8];
        #define INITH(q) h[q] = b1v[q];
        INITH(0) INITH(1) INITH(2) INITH(3) INITH(4) INITH(5) INITH(6) INITH(7)
        #undef INITH
        #define L1Q(i, q) h[q] = ffma4(xi, w1v[(i) * 8 + (q)], h[q]);
        #define L1I(i, xv) { const float xi = (xv); \
            L1Q(i,0) L1Q(i,1) L1Q(i,2) L1Q(i,3) L1Q(i,4) L1Q(i,5) L1Q(i,6) L1Q(i,7) }
        L1I(0, x0g) L1I(1, x1g) L1I(2, x2g) L1I(3, x3g) L1I(4, x4g)
        #undef L1I
        #undef L1Q
        TANH4(h[0]) TANH4(h[1]) TANH4(h[2]) TANH4(h[3])
        TANH4(h[4]) TANH4(h[5]) TANH4(h[6]) TANH4(h[7])

        // ---- pack bf16, stage to wave-private LDS [struct][k] ----
        uint4* wp = (uint4*)(hrow + lane * 40);
        wp[0] = make_uint4(pack2(h[0].x,h[0].y), pack2(h[0].z,h[0].w),
                           pack2(h[1].x,h[1].y), pack2(h[1].z,h[1].w));
        wp[1] = make_uint4(pack2(h[2].x,h[2].y), pack2(h[2].z,h[2].w),
                           pack2(h[3].x,h[3].y), pack2(h[3].z,h[3].w));
        wp[2] = make_uint4(pack2(h[4].x,h[4].y), pack2(h[4].z,h[4].w),
                           pack2(h[5].x,h[5].y), pack2(h[5].z,h[5].w));
        wp[3] = make_uint4(pack2(h[6].x,h[6].y), pack2(h[6].z,h[6].w),
                           pack2(h[7].x,h[7].y), pack2(h[7].z,h[7].w));
        __builtin_amdgcn_wave_barrier();   // DS in-order per wave; no reorder

        // ---- B-fragments + MFMA (2 tiles of 32 structs, K=32 in 2 steps) ----
        const unsigned short* rb = hrow + half * 8;
        const short8 b00 = __builtin_bit_cast(short8, *(const uint4*)(rb + l31 * 40));
        const short8 b01 = __builtin_bit_cast(short8, *(const uint4*)(rb + l31 * 40 + 16));
        const short8 b10 = __builtin_bit_cast(short8, *(const uint4*)(rb + (32 + l31) * 40));
        const short8 b11 = __builtin_bit_cast(short8, *(const uint4*)(rb + (32 + l31) * 40 + 16));

        f32x16 acc0 = {b2q0.x, b2q0.y, b2q0.z, b2q0.w,
                       b2q1.x, b2q1.y, b2q1.z, b2q1.w,
                       b2q2.x, b2q2.y, b2q2.z, b2q2.w,
                       b2q3.x, b2q3.y, b2q3.z, b2q3.w};
        f32x16 acc1 = acc0;
        acc0 = __builtin_amdgcn_mfma_f32_32x32x16_bf16(af0, b00, acc0, 0, 0, 0);
        acc0 = __builtin_amdgcn_mfma_f32_32x32x16_bf16(af1, b01, acc0, 0, 0, 0);
        acc1 = __builtin_amdgcn_mfma_f32_32x32x16_bf16(af0, b10, acc1, 0, 0, 0);
        acc1 = __builtin_amdgcn_mfma_f32_32x32x16_bf16(af1, b11, acc1, 0, 0, 0);

        // ---- tanh + layer 3 (16 m-rows per lane, partner holds other 16) ----
        float p0 = 0.f, p1 = 0.f;
        #define EP(r, wq, comp) { p0 = fmaf(fast_tanh(acc0[r]), (wq).comp, p0); \
                                  p1 = fmaf(fast_tanh(acc1[r]), (wq).comp, p1); }
        EP(0,w3q0,x) EP(1,w3q0,y) EP(2,w3q0,z) EP(3,w3q0,w)
        EP(4,w3q1,x) EP(5,w3q1,y) EP(6,w3q1,z) EP(7,w3q1,w)
        EP(8,w3q2,x) EP(9,w3q2,y) EP(10,w3q2,z) EP(11,w3q2,w)
        EP(12,w3q3,x) EP(13,w3q3,y) EP(14,w3q3,z) EP(15,w3q3,w)
        #undef EP
        p0 += __shfl_xor(p0, 32);
        p1 += __shfl_xor(p1, 32);

        if (lane < 32) {
            const int st0 = base + l31;
            const int st1 = base + 32 + l31;
            if (st0 < send) out[(size_t)st0 * NA + a] = p0 + bias3;
            if (st1 < send) out[(size_t)st1 * NA + a] = p1 + bias3;
        }
    }
}

extern "C" void kernel_launch(void* const* d_in, const int* in_sizes, int n_in,
                              void* d_out, int out_size, void* d_ws, size_t ws_size,
                              hipStream_t stream) {
    const float* g  = (const float*)d_in[0];
    const float* W1 = (const float*)d_in[1];
    const float* b1 = (const float*)d_in[2];
    const float* W2 = (const float*)d_in[3];
    const float* b2 = (const float*)d_in[4];
    const float* W3 = (const float*)d_in[5];
    const float* b3 = (const float*)d_in[6];
    float* out = (float*)d_out;
    mlp_mfma<<<dim3(NA * 2), dim3(256), 0, stream>>>(g, W1, b1, W2, b2, W3, b3, out);
}

// Round 9
// 137.037 us; speedup vs baseline: 1.0224x; 1.0224x over previous
//
#include <hip/hip_runtime.h>
#include <hip/hip_bf16.h>

#define NS_TOT 2000
#define NA 1000
#define NI 5
#define NH 32
#define SHALF 1000                 // structs per block (two blocks per atom)

typedef __attribute__((ext_vector_type(2)))  float f32x2;
typedef __attribute__((ext_vector_type(8)))  short short8;   // 8 bf16 = 4 VGPR
typedef __attribute__((ext_vector_type(16))) float f32x16;   // MFMA 32x32 acc

struct f4pair  { f32x2 a, b; };        // float4 reinterpreted as 2 pairs
struct accpair { f32x2 p[8]; };        // f32x16 reinterpreted as 8 pairs

// Packed Pade[5/4] tanh: t = x*(945+105z+z^2)/(945+420z+15z^2), z=x^2,
// clamped to [-1,1]. Max abs err ~1e-3 (near |x|~3.8); clamp covers |x|>4.07
// where the rational exceeds 1 (it stays >1 and -> x/15, so med3 is safe).
// R8 post-mortem: hand-written v_pk_* asm without explicit op_sel_hi:[1,1,1]
// gave element-swapped semantics (absmax 3.18). Native ext-vector arithmetic
// has guaranteed element-wise semantics and lets the compiler emit v_pk_*
// itself (correct modifiers), falling back to scalar fma if not.
__device__ __forceinline__ f32x2 tanh_pk(f32x2 X) {
    f32x2 z = X * X;
    f32x2 n = (z + 105.0f) * z + 945.0f;          // z^2 + 105 z + 945
    f32x2 d = (z * 15.0f + 420.0f) * z + 945.0f;  // 15 z^2 + 420 z + 945
    f32x2 r;
    r.x = __builtin_amdgcn_rcpf(d.x);
    r.y = __builtin_amdgcn_rcpf(d.y);
    f32x2 t = X * n * r;
    t.x = __builtin_amdgcn_fmed3f(t.x, -1.0f, 1.0f);
    t.y = __builtin_amdgcn_fmed3f(t.y, -1.0f, 1.0f);
    return t;
}

__device__ __forceinline__ float4 ffma4(float s, float4 w, float4 acc) {
    acc.x = fmaf(s, w.x, acc.x);
    acc.y = fmaf(s, w.y, acc.y);
    acc.z = fmaf(s, w.z, acc.z);
    acc.w = fmaf(s, w.w, acc.w);
    return acc;
}

__device__ __forceinline__ unsigned short f2bf_rne(float x) {
    unsigned u = __float_as_uint(x);
    unsigned r = u + 0x7FFFu + ((u >> 16) & 1u);
    return (unsigned short)(r >> 16);
}

__device__ __forceinline__ unsigned pack2(float a, float b) {
    __hip_bfloat162 p = __float22bfloat162_rn(make_float2(a, b));
    unsigned u; __builtin_memcpy(&u, &p, 4); return u;
}

__global__ __attribute__((amdgpu_flat_work_group_size(256, 256),
                          amdgpu_waves_per_eu(4, 8)))
void mlp_mfma(
    const float* __restrict__ g,
    const float* __restrict__ W1, const float* __restrict__ b1,
    const float* __restrict__ W2, const float* __restrict__ b2,
    const float* __restrict__ W3, const float* __restrict__ b3,
    float* __restrict__ out)
{
    const int bid   = blockIdx.x;
    const int araw  = bid % NA;
    const int chunk = bid / NA;              // 0 or 1: which s-half
    const int a = (araw >> 3) + 125 * (araw & 7);   // same-XCD atom swizzle
    const int t = threadIdx.x;
    const int lane = t & 63, wid = t >> 6;
    const int l31 = lane & 31, half = lane >> 5;

    const int sbase_blk = chunk * SHALF;
    const int send      = sbase_blk + SHALF;

    __shared__ __align__(16) unsigned short sW2T[NH * NH];   // W2^T bf16 [m][k]
    __shared__ __align__(16) float sB2[NH];
    __shared__ __align__(16) float sW3[NH];
    __shared__ __align__(16) unsigned short sH[4][64 * 40];  // wave-private

    for (int idx = t; idx < NH * NH; idx += 256) {
        const int i = idx >> 5, j = idx & 31;
        sW2T[j * NH + i] = f2bf_rne(W2[(size_t)a * NH * NH + idx]);
    }
    if (t < NH) { sB2[t] = b2[a * NH + t]; sW3[t] = W3[a * NH + t]; }
    __syncthreads();

    // persistent fragments
    const short8 af0 = __builtin_bit_cast(short8, *(const uint4*)(sW2T + l31 * NH + half * 8));
    const short8 af1 = __builtin_bit_cast(short8, *(const uint4*)(sW2T + l31 * NH + 16 + half * 8));
    const float4 b2q0 = ((const float4*)sB2)[0 + half];
    const float4 b2q1 = ((const float4*)sB2)[2 + half];
    const float4 b2q2 = ((const float4*)sB2)[4 + half];
    const float4 b2q3 = ((const float4*)sB2)[6 + half];
    const float4 w3q0 = ((const float4*)sW3)[0 + half];
    const float4 w3q1 = ((const float4*)sW3)[2 + half];
    const float4 w3q2 = ((const float4*)sW3)[4 + half];
    const float4 w3q3 = ((const float4*)sW3)[6 + half];
    const float bias3 = b3[a];

    // w3 as pairs (acc element pair (2r,2r+1) <-> w3 quad component pair)
    const f4pair w3p0 = __builtin_bit_cast(f4pair, w3q0);
    const f4pair w3p1 = __builtin_bit_cast(f4pair, w3q1);
    const f4pair w3p2 = __builtin_bit_cast(f4pair, w3q2);
    const f4pair w3p3 = __builtin_bit_cast(f4pair, w3q3);

    const float4* w1v = (const float4*)(W1 + (size_t)a * NI * NH);
    const float4* b1v = (const float4*)(b1 + (size_t)a * NH);

    unsigned short* hrow = sH[wid];

    for (int it = 0; it < 4; ++it) {
        const int base = sbase_blk + it * 256 + wid * 64;
        const int s = base + lane;
        const int sl = (s < send) ? s : (send - 1);

        const float* gp = g + ((size_t)sl * NA + a) * NI;
        const float x0g = gp[0], x1g = gp[1], x2g = gp[2], x3g = gp[3], x4g = gp[4];

        // ---- layer 1: 5 -> 32 (VALU, scalar weights) ----
        float4 h[8];
        #define INITH(q) h[q] = b1v[q];
        INITH(0) INITH(1) INITH(2) INITH(3) INITH(4) INITH(5) INITH(6) INITH(7)
        #undef INITH
        #define L1Q(i, q) h[q] = ffma4(xi, w1v[(i) * 8 + (q)], h[q]);
        #define L1I(i, xv) { const float xi = (xv); \
            L1Q(i,0) L1Q(i,1) L1Q(i,2) L1Q(i,3) L1Q(i,4) L1Q(i,5) L1Q(i,6) L1Q(i,7) }
        L1I(0, x0g) L1I(1, x1g) L1I(2, x2g) L1I(3, x3g) L1I(4, x4g)
        #undef L1I
        #undef L1Q

        // ---- tanh (packed Pade) on 16 pairs ----
        f32x2 th[16];
        #define TH(q) { f4pair hp = __builtin_bit_cast(f4pair, h[q]); \
            th[2*(q)]   = tanh_pk(hp.a); \
            th[2*(q)+1] = tanh_pk(hp.b); }
        TH(0) TH(1) TH(2) TH(3) TH(4) TH(5) TH(6) TH(7)
        #undef TH

        // ---- pack bf16, stage to wave-private LDS [struct][k] ----
        uint4* wp = (uint4*)(hrow + lane * 40);
        wp[0] = make_uint4(pack2(th[0].x,th[0].y), pack2(th[1].x,th[1].y),
                           pack2(th[2].x,th[2].y), pack2(th[3].x,th[3].y));
        wp[1] = make_uint4(pack2(th[4].x,th[4].y), pack2(th[5].x,th[5].y),
                           pack2(th[6].x,th[6].y), pack2(th[7].x,th[7].y));
        wp[2] = make_uint4(pack2(th[8].x,th[8].y), pack2(th[9].x,th[9].y),
                           pack2(th[10].x,th[10].y), pack2(th[11].x,th[11].y));
        wp[3] = make_uint4(pack2(th[12].x,th[12].y), pack2(th[13].x,th[13].y),
                           pack2(th[14].x,th[14].y), pack2(th[15].x,th[15].y));
        __builtin_amdgcn_wave_barrier();

        // ---- B-fragments + MFMA ----
        const unsigned short* rb = hrow + half * 8;
        const short8 b00 = __builtin_bit_cast(short8, *(const uint4*)(rb + l31 * 40));
        const short8 b01 = __builtin_bit_cast(short8, *(const uint4*)(rb + l31 * 40 + 16));
        const short8 b10 = __builtin_bit_cast(short8, *(const uint4*)(rb + (32 + l31) * 40));
        const short8 b11 = __builtin_bit_cast(short8, *(const uint4*)(rb + (32 + l31) * 40 + 16));

        f32x16 acc0 = {b2q0.x, b2q0.y, b2q0.z, b2q0.w,
                       b2q1.x, b2q1.y, b2q1.z, b2q1.w,
                       b2q2.x, b2q2.y, b2q2.z, b2q2.w,
                       b2q3.x, b2q3.y, b2q3.z, b2q3.w};
        f32x16 acc1 = acc0;
        acc0 = __builtin_amdgcn_mfma_f32_32x32x16_bf16(af0, b00, acc0, 0, 0, 0);
        acc0 = __builtin_amdgcn_mfma_f32_32x32x16_bf16(af1, b01, acc0, 0, 0, 0);
        acc1 = __builtin_amdgcn_mfma_f32_32x32x16_bf16(af0, b10, acc1, 0, 0, 0);
        acc1 = __builtin_amdgcn_mfma_f32_32x32x16_bf16(af1, b11, acc1, 0, 0, 0);

        // ---- packed tanh + packed layer-3 dot ----
        const accpair ap0 = __builtin_bit_cast(accpair, acc0);
        const accpair ap1 = __builtin_bit_cast(accpair, acc1);
        f32x2 p0 = {0.f, 0.f}, p1 = {0.f, 0.f};
        #define EPP(r, wpair) { \
            p0 += tanh_pk(ap0.p[r]) * (wpair); \
            p1 += tanh_pk(ap1.p[r]) * (wpair); }
        EPP(0, w3p0.a) EPP(1, w3p0.b)
        EPP(2, w3p1.a) EPP(3, w3p1.b)
        EPP(4, w3p2.a) EPP(5, w3p2.b)
        EPP(6, w3p3.a) EPP(7, w3p3.b)
        #undef EPP
        float e0 = p0.x + p0.y;
        float e1 = p1.x + p1.y;
        e0 += __shfl_xor(e0, 32);
        e1 += __shfl_xor(e1, 32);

        if (lane < 32) {
            const int st0 = base + l31;
            const int st1 = base + 32 + l31;
            if (st0 < send) out[(size_t)st0 * NA + a] = e0 + bias3;
            if (st1 < send) out[(size_t)st1 * NA + a] = e1 + bias3;
        }
    }
}

extern "C" void kernel_launch(void* const* d_in, const int* in_sizes, int n_in,
                              void* d_out, int out_size, void* d_ws, size_t ws_size,
                              hipStream_t stream) {
    const float* g  = (const float*)d_in[0];
    const float* W1 = (const float*)d_in[1];
    const float* b1 = (const float*)d_in[2];
    const float* W2 = (const float*)d_in[3];
    const float* b2 = (const float*)d_in[4];
    const float* W3 = (const float*)d_in[5];
    const float* b3 = (const float*)d_in[6];
    float* out = (float*)d_out;
    mlp_mfma<<<dim3(NA * 2), dim3(256), 0, stream>>>(g, W1, b1, W2, b2, W3, b3, out);
}